// Round 1
// baseline (322.816 us; speedup 1.0000x reference)
//
#include <hip/hip_runtime.h>
#include <stdint.h>

#define T_DIM 2048
#define B_DIM 128
#define H_DIM 128
#define QH_DIM 1024
#define NF 32
#define KW 31
#define TT 32          // t-tile per block in k2
#define TW 8           // t's per wave in k2

__device__ __forceinline__ float fast_tanh(float x) {
    // tanh(x) = 1 - 2/(1+e^{2x}); saturates correctly via inf/0 behavior of exp/rcp
    float e = __expf(2.0f * x);
    return 1.0f - 2.0f * __builtin_amdgcn_rcpf(1.0f + e);
}

// k0: G[h,k] = sum_f Wa[h,f] * conv_w[f,0,k]   (fold conv filter through Wa)
__global__ void k0_G(const float* __restrict__ Wa, const float* __restrict__ conv_w,
                     float* __restrict__ G) {
    int gid = blockIdx.x * blockDim.x + threadIdx.x;
    if (gid >= H_DIM * KW) return;
    int h = gid / KW, k = gid - h * KW;
    float acc = 0.0f;
    #pragma unroll
    for (int f = 0; f < NF; ++f) acc = fmaf(Wa[h * NF + f], conv_w[f * KW + k], acc);
    G[gid] = acc;
}

// k1: qb[b,h] = query[b,:]·Wq[h,:] + bq[h] + ba[h] + score_b[h] + Wa[h,:]·conv_b
//      (all t-independent additive terms folded into one base vector)
__global__ __launch_bounds__(512)
void k1_query(const float* __restrict__ query, const float* __restrict__ Wq,
              const float* __restrict__ bq, const float* __restrict__ Wa,
              const float* __restrict__ conv_b, const float* __restrict__ ba,
              const float* __restrict__ score_b, float* __restrict__ qb) {
    const int b = blockIdx.x, tid = threadIdx.x;
    const int h = tid & 127, qtr = tid >> 7;
    __shared__ __align__(16) float qrow[QH_DIM];
    __shared__ float partial[512];
    for (int i = tid; i < QH_DIM; i += 512) qrow[i] = query[b * QH_DIM + i];
    __syncthreads();
    const float4* wq4 = (const float4*)(Wq + (size_t)h * QH_DIM + qtr * 256);
    const float4* q4 = (const float4*)(qrow + qtr * 256);
    float acc = 0.0f;
    #pragma unroll 4
    for (int j = 0; j < 64; ++j) {
        float4 w = wq4[j], q = q4[j];
        acc += w.x * q.x + w.y * q.y + w.z * q.z + w.w * q.w;
    }
    if (qtr == 0) {
        float cb = bq[h] + ba[h] + score_b[h];
        #pragma unroll
        for (int f = 0; f < NF; ++f) cb = fmaf(Wa[h * NF + f], conv_b[f], cb);
        acc += cb;
    }
    partial[tid] = acc;
    __syncthreads();
    if (tid < 128) qb[b * H_DIM + h] = partial[h] + partial[h + 128] + partial[h + 256] + partial[h + 384];
}

// k2: s[b,t] = sum_h score_w[h]*tanh(enc[t,b,h] + qb[b,h] + sum_k G[h,k]*cum[b,t-15+k])
// Each wave: lane owns h=lane and h=lane+64, handles TW consecutive t's.
// G rows and the wave's cum window live in registers (static indexing via full unroll).
__global__ __launch_bounds__(256)
void k2_score(const float* __restrict__ enc, const float* __restrict__ cum,
              const float* __restrict__ G, const float* __restrict__ qb,
              const float* __restrict__ score_w, float* __restrict__ s_out) {
    const int b = blockIdx.y;
    const int t0 = blockIdx.x * TT;
    const int tid = threadIdx.x;
    __shared__ float Gs[H_DIM * KW];
    __shared__ float base_s[H_DIM];
    __shared__ float sw_s[H_DIM];
    __shared__ float cw[TT + KW - 1];   // 62

    for (int i = tid; i < H_DIM * KW; i += 256) Gs[i] = G[i];
    if (tid < H_DIM) {
        base_s[tid] = qb[b * H_DIM + tid];
        sw_s[tid] = score_w[tid];
    }
    if (tid < TT + KW - 1) {
        int t = t0 - (KW / 2) + tid;
        cw[tid] = (t >= 0 && t < T_DIM) ? cum[b * T_DIM + t] : 0.0f;
    }
    __syncthreads();

    const int wave = tid >> 6, lane = tid & 63;
    float g0r[KW], g1r[KW];
    #pragma unroll
    for (int k = 0; k < KW; ++k) {
        g0r[k] = Gs[lane * KW + k];
        g1r[k] = Gs[(lane + 64) * KW + k];
    }
    float cwr[TW + KW - 1];             // 38, wave-local sliding window
    #pragma unroll
    for (int j = 0; j < TW + KW - 1; ++j) cwr[j] = cw[wave * TW + j];
    const float b0 = base_s[lane], b1 = base_s[lane + 64];
    const float w0 = sw_s[lane], w1 = sw_s[lane + 64];

    const int tw0 = t0 + wave * TW;
    const float* ep0 = enc + ((size_t)tw0 * B_DIM + b) * H_DIM;

    #pragma unroll
    for (int it = 0; it < TW; ++it) {
        const float* ep = ep0 + (size_t)it * (B_DIM * H_DIM);
        float acc0 = b0 + ep[lane];
        float acc1 = b1 + ep[lane + 64];
        #pragma unroll
        for (int k = 0; k < KW; ++k) {
            const float c = cwr[it + k];
            acc0 = fmaf(g0r[k], c, acc0);
            acc1 = fmaf(g1r[k], c, acc1);
        }
        float p = w0 * fast_tanh(acc0) + w1 * fast_tanh(acc1);
        #pragma unroll
        for (int m = 32; m >= 1; m >>= 1) p += __shfl_xor(p, m, 64);
        if (lane == 0) s_out[b * T_DIM + tw0 + it] = p;
    }
}

// k3: masked softmax over t per batch row; writes alignment (in place over raw s)
// and cumulative_alignment. Runtime-detects mask element layout (byte/int32/f32).
__global__ __launch_bounds__(256)
void k3_softmax(float* __restrict__ s_align, const void* __restrict__ mask,
                const float* __restrict__ cum_in, float* __restrict__ cum_out) {
    const int b = blockIdx.x, tid = threadIdx.x;
    const int wave = tid >> 6, lane = tid & 63;

    // layout probe: first 64 u32 words of the mask buffer
    uint32_t u = ((const uint32_t*)mask)[lane];
    unsigned long long hi = __ballot(u > 1u);
    unsigned long long nf = __ballot(u != 0u && u != 0x3f800000u);
    int layout = (hi == 0ull) ? 0 : ((nf == 0ull) ? 2 : 1);  // 0=int32, 1=byte, 2=float

    float v[8];
    float mx = -__builtin_inff();
    #pragma unroll
    for (int i = 0; i < 8; ++i) {
        int idx = b * T_DIM + tid + i * 256;
        bool m;
        if (layout == 0)      m = ((const int32_t*)mask)[idx] != 0;
        else if (layout == 1) m = ((const uint8_t*)mask)[idx] != 0;
        else                  m = ((const float*)mask)[idx] != 0.0f;
        v[i] = m ? -__builtin_inff() : s_align[idx];
        mx = fmaxf(mx, v[i]);
    }
    #pragma unroll
    for (int s = 32; s >= 1; s >>= 1) mx = fmaxf(mx, __shfl_xor(mx, s, 64));
    __shared__ float redm[4], reds[4];
    if (lane == 0) redm[wave] = mx;
    __syncthreads();
    mx = fmaxf(fmaxf(redm[0], redm[1]), fmaxf(redm[2], redm[3]));

    float e[8], sum = 0.0f;
    #pragma unroll
    for (int i = 0; i < 8; ++i) { e[i] = __expf(v[i] - mx); sum += e[i]; }
    #pragma unroll
    for (int s = 32; s >= 1; s >>= 1) sum += __shfl_xor(sum, s, 64);
    if (lane == 0) reds[wave] = sum;
    __syncthreads();
    sum = reds[0] + reds[1] + reds[2] + reds[3];
    const float inv = 1.0f / sum;

    #pragma unroll
    for (int i = 0; i < 8; ++i) {
        int idx = b * T_DIM + tid + i * 256;
        float a = e[i] * inv;
        s_align[idx] = a;
        cum_out[idx] = cum_in[idx] + a;
    }
}

// k4: context[b,h] = sum_t alignment[b,t] * enc[t,b,h]; partial per (b, t-chunk) block,
// combined with one atomicAdd per (block, h).
__global__ __launch_bounds__(256)
void k4_context(const float* __restrict__ enc, const float* __restrict__ align,
                float* __restrict__ ctx) {
    const int b = blockIdx.y, chunk = blockIdx.x;
    const int tid = threadIdx.x;
    const int h = tid & 127, half = tid >> 7;
    __shared__ float al[128];
    __shared__ float part[128];
    if (tid < 128) al[tid] = align[b * T_DIM + chunk * 128 + tid];
    __syncthreads();
    const int tb = chunk * 128 + half * 64;
    const float* ep = enc + ((size_t)tb * B_DIM + b) * H_DIM + h;
    float acc = 0.0f;
    #pragma unroll 8
    for (int i = 0; i < 64; ++i) {
        acc = fmaf(al[half * 64 + i], ep[(size_t)i * (B_DIM * H_DIM)], acc);
    }
    if (half == 0) part[h] = acc;
    __syncthreads();
    if (half == 1) atomicAdd(&ctx[b * H_DIM + h], acc + part[h]);
}

extern "C" void kernel_launch(void* const* d_in, const int* in_sizes, int n_in,
                              void* d_out, int out_size, void* d_ws, size_t ws_size,
                              hipStream_t stream) {
    const float* enc     = (const float*)d_in[0];
    const void*  mask    = d_in[1];
    const float* query   = (const float*)d_in[2];
    const float* cum     = (const float*)d_in[3];
    const float* conv_w  = (const float*)d_in[4];
    const float* conv_b  = (const float*)d_in[5];
    const float* Wq      = (const float*)d_in[6];
    const float* bq      = (const float*)d_in[7];
    const float* Wa      = (const float*)d_in[8];
    const float* ba      = (const float*)d_in[9];
    const float* score_w = (const float*)d_in[10];
    const float* score_b = (const float*)d_in[11];

    float* ctx_out   = (float*)d_out;                    // [B,H]   16384
    float* cum_out   = ctx_out + B_DIM * H_DIM;          // [B,T]   262144
    float* align_out = cum_out + B_DIM * T_DIM;          // [B,T]   262144

    float* G  = (float*)d_ws;                            // 3968 floats (pad to 4096)
    float* qb = G + 4096;                                // 16384 floats

    hipMemsetAsync(ctx_out, 0, B_DIM * H_DIM * sizeof(float), stream);
    k0_G<<<16, 256, 0, stream>>>(Wa, conv_w, G);
    k1_query<<<B_DIM, 512, 0, stream>>>(query, Wq, bq, Wa, conv_b, ba, score_b, qb);
    k2_score<<<dim3(T_DIM / TT, B_DIM), 256, 0, stream>>>(enc, cum, G, qb, score_w, align_out);
    k3_softmax<<<B_DIM, 256, 0, stream>>>(align_out, mask, cum, cum_out);
    k4_context<<<dim3(16, B_DIM), 256, 0, stream>>>(enc, align_out, ctx_out);
}

// Round 2
// 284.806 us; speedup vs baseline: 1.1335x; 1.1335x over previous
//
#include <hip/hip_runtime.h>
#include <stdint.h>

#define T_DIM 2048
#define B_DIM 128
#define H_DIM 128
#define QH_DIM 1024
#define NF 32
#define KW 31
#define TT 32          // t-tile per block in k2
#define TW 8           // t's per wave in k2

__device__ __forceinline__ float fast_tanh(float x) {
    float e = __expf(2.0f * x);
    return 1.0f - 2.0f * __builtin_amdgcn_rcpf(1.0f + e);
}

__device__ __forceinline__ float rfl(float x) {
    return __uint_as_float(__builtin_amdgcn_readfirstlane(__float_as_uint(x)));
}

// k0: G[k][h] = sum_f Wa[h,f] * conv_w[f,0,k]  — [k][h] layout for coalesced k2 staging
__global__ void k0_G(const float* __restrict__ Wa, const float* __restrict__ conv_w,
                     float* __restrict__ G) {
    int gid = blockIdx.x * blockDim.x + threadIdx.x;
    if (gid >= H_DIM * KW) return;
    int k = gid >> 7, h = gid & 127;
    float acc = 0.0f;
    #pragma unroll
    for (int f = 0; f < NF; ++f) acc = fmaf(Wa[h * NF + f], conv_w[f * KW + k], acc);
    G[gid] = acc;
}

// k1: qb[b,h] = query[b,:]·Wq[h,:] + bq[h] + ba[h] + score_b[h] + Wa[h,:]·conv_b
__global__ __launch_bounds__(512)
void k1_query(const float* __restrict__ query, const float* __restrict__ Wq,
              const float* __restrict__ bq, const float* __restrict__ Wa,
              const float* __restrict__ conv_b, const float* __restrict__ ba,
              const float* __restrict__ score_b, float* __restrict__ qb) {
    const int b = blockIdx.x, tid = threadIdx.x;
    const int h = tid & 127, qtr = tid >> 7;
    __shared__ __align__(16) float qrow[QH_DIM];
    __shared__ float partial[512];
    for (int i = tid; i < QH_DIM; i += 512) qrow[i] = query[b * QH_DIM + i];
    __syncthreads();
    const float4* wq4 = (const float4*)(Wq + (size_t)h * QH_DIM + qtr * 256);
    const float4* q4 = (const float4*)(qrow + qtr * 256);
    float acc = 0.0f;
    #pragma unroll 4
    for (int j = 0; j < 64; ++j) {
        float4 w = wq4[j], q = q4[j];
        acc += w.x * q.x + w.y * q.y + w.z * q.z + w.w * q.w;
    }
    if (qtr == 0) {
        float cb = bq[h] + ba[h] + score_b[h];
        #pragma unroll
        for (int f = 0; f < NF; ++f) cb = fmaf(Wa[h * NF + f], conv_b[f], cb);
        acc += cb;
    }
    partial[tid] = acc;
    __syncthreads();
    if (tid < 128) qb[b * H_DIM + h] = partial[h] + partial[h + 128] + partial[h + 256] + partial[h + 384];
}

// k2: s[b,t] = sum_h score_w[h]*tanh(enc[t,b,h] + qb[b,h] + sum_k G[k][h]*cum[b,t-15+k])
// Lane owns h = {2l, 2l+1} (float2 everywhere). cum window lives in SGPRs
// (readfirstlane — wave-uniform). G loaded from LDS in two k-chunks of <=16
// (32 VGPRs peak) to guarantee registerization.
__global__ __launch_bounds__(256, 4)
void k2_score(const float* __restrict__ enc, const float* __restrict__ cum,
              const float* __restrict__ G, const float* __restrict__ qb,
              const float* __restrict__ score_w, float* __restrict__ s_out) {
    const int b = blockIdx.y;
    const int t0 = blockIdx.x * TT;
    const int tid = threadIdx.x;
    const int l = tid & 63, wv = tid >> 6;

    __shared__ float Gs[KW * H_DIM];    // [k][h], 15872 B
    __shared__ float cw[TT + KW - 1];   // 62

    #pragma unroll
    for (int i = tid; i < KW * H_DIM; i += 256) Gs[i] = G[i];
    if (tid < TT + KW - 1) {
        int t = t0 - (KW / 2) + tid;
        cw[tid] = (t >= 0 && t < T_DIM) ? cum[b * T_DIM + t] : 0.0f;
    }
    __syncthreads();

    // wave-uniform cum window -> SGPRs
    float sc[TW + KW - 1];              // 38
    #pragma unroll
    for (int j = 0; j < TW + KW - 1; ++j) sc[j] = rfl(cw[wv * TW + j]);

    const float2 base = *(const float2*)(qb + b * H_DIM + 2 * l);
    const float2 w2 = *(const float2*)(score_w + 2 * l);

    const int tw0 = t0 + wv * TW;
    const float* ep0 = enc + ((size_t)tw0 * B_DIM + b) * H_DIM + 2 * l;

    // init acc with base + enc (enc loads issue up-front, independent)
    float2 acc[TW];
    #pragma unroll
    for (int it = 0; it < TW; ++it) {
        const float2 e = *(const float2*)(ep0 + (size_t)it * (B_DIM * H_DIM));
        acc[it].x = base.x + e.x;
        acc[it].y = base.y + e.y;
    }

    // FIR chunk 1: k = 0..15
    {
        float2 g[16];
        #pragma unroll
        for (int kk = 0; kk < 16; ++kk) g[kk] = *(const float2*)(&Gs[kk * H_DIM + 2 * l]);
        #pragma unroll
        for (int kk = 0; kk < 16; ++kk) {
            #pragma unroll
            for (int it = 0; it < TW; ++it) {
                const float c = sc[it + kk];
                acc[it].x = fmaf(g[kk].x, c, acc[it].x);
                acc[it].y = fmaf(g[kk].y, c, acc[it].y);
            }
        }
    }
    // FIR chunk 2: k = 16..30
    {
        float2 g[15];
        #pragma unroll
        for (int kk = 0; kk < 15; ++kk) g[kk] = *(const float2*)(&Gs[(16 + kk) * H_DIM + 2 * l]);
        #pragma unroll
        for (int kk = 0; kk < 15; ++kk) {
            #pragma unroll
            for (int it = 0; it < TW; ++it) {
                const float c = sc[it + 16 + kk];
                acc[it].x = fmaf(g[kk].x, c, acc[it].x);
                acc[it].y = fmaf(g[kk].y, c, acc[it].y);
            }
        }
    }

    // tanh + score + cross-lane reduce (h = 2l, 2l+1 over 64 lanes = all 128 h)
    #pragma unroll
    for (int it = 0; it < TW; ++it) {
        float p = w2.x * fast_tanh(acc[it].x) + w2.y * fast_tanh(acc[it].y);
        #pragma unroll
        for (int m = 32; m >= 1; m >>= 1) p += __shfl_xor(p, m, 64);
        if (l == 0) s_out[b * T_DIM + tw0 + it] = p;
    }
}

// k3: masked softmax over t per batch row (in place over raw s) + cum update.
__global__ __launch_bounds__(256)
void k3_softmax(float* __restrict__ s_align, const void* __restrict__ mask,
                const float* __restrict__ cum_in, float* __restrict__ cum_out) {
    const int b = blockIdx.x, tid = threadIdx.x;
    const int wave = tid >> 6, lane = tid & 63;

    // layout probe: first 64 u32 words of the mask buffer
    uint32_t u = ((const uint32_t*)mask)[lane];
    unsigned long long hi = __ballot(u > 1u);
    unsigned long long nf = __ballot(u != 0u && u != 0x3f800000u);
    int layout = (hi == 0ull) ? 0 : ((nf == 0ull) ? 2 : 1);  // 0=int32, 1=byte, 2=float

    float v[8];
    float mx = -__builtin_inff();
    #pragma unroll
    for (int i = 0; i < 8; ++i) {
        int idx = b * T_DIM + tid + i * 256;
        bool m;
        if (layout == 0)      m = ((const int32_t*)mask)[idx] != 0;
        else if (layout == 1) m = ((const uint8_t*)mask)[idx] != 0;
        else                  m = ((const float*)mask)[idx] != 0.0f;
        v[i] = m ? -__builtin_inff() : s_align[idx];
        mx = fmaxf(mx, v[i]);
    }
    #pragma unroll
    for (int s = 32; s >= 1; s >>= 1) mx = fmaxf(mx, __shfl_xor(mx, s, 64));
    __shared__ float redm[4], reds[4];
    if (lane == 0) redm[wave] = mx;
    __syncthreads();
    mx = fmaxf(fmaxf(redm[0], redm[1]), fmaxf(redm[2], redm[3]));

    float e[8], sum = 0.0f;
    #pragma unroll
    for (int i = 0; i < 8; ++i) { e[i] = __expf(v[i] - mx); sum += e[i]; }
    #pragma unroll
    for (int s = 32; s >= 1; s >>= 1) sum += __shfl_xor(sum, s, 64);
    if (lane == 0) reds[wave] = sum;
    __syncthreads();
    sum = reds[0] + reds[1] + reds[2] + reds[3];
    const float inv = 1.0f / sum;

    #pragma unroll
    for (int i = 0; i < 8; ++i) {
        int idx = b * T_DIM + tid + i * 256;
        float a = e[i] * inv;
        s_align[idx] = a;
        cum_out[idx] = cum_in[idx] + a;
    }
}

// k4: context[b,h] = sum_t alignment[b,t] * enc[t,b,h]
// float4 along h (32 lanes cover 128 h); 8 t-slots; 16 independent float4
// loads in flight per thread; LDS tree-reduce; 4 atomics/lane at the end.
__global__ __launch_bounds__(256)
void k4_context(const float* __restrict__ enc, const float* __restrict__ align,
                float* __restrict__ ctx) {
    const int b = blockIdx.y, t0 = blockIdx.x * 128;
    const int tid = threadIdx.x;
    const int q = tid & 31, r = tid >> 5;   // q: h/4, r: t-slot 0..7
    __shared__ float al[128];
    if (tid < 128) al[tid] = align[b * T_DIM + t0 + tid];
    __syncthreads();
    const float* ep = enc + ((size_t)(t0 + r) * B_DIM + b) * H_DIM + 4 * q;
    float4 acc = {0.0f, 0.0f, 0.0f, 0.0f};
    #pragma unroll
    for (int i = 0; i < 16; ++i) {
        const float a = al[r + 8 * i];
        const float4 v = *(const float4*)(ep + (size_t)(8 * i) * (B_DIM * H_DIM));
        acc.x = fmaf(a, v.x, acc.x);
        acc.y = fmaf(a, v.y, acc.y);
        acc.z = fmaf(a, v.z, acc.z);
        acc.w = fmaf(a, v.w, acc.w);
    }
    __shared__ float4 part[8][32];
    part[r][q] = acc;
    __syncthreads();
    if (tid < 32) {
        float4 s = part[0][q];
        #pragma unroll
        for (int rr = 1; rr < 8; ++rr) {
            float4 p = part[rr][q];
            s.x += p.x; s.y += p.y; s.z += p.z; s.w += p.w;
        }
        float* dst = ctx + b * H_DIM + 4 * q;
        atomicAdd(dst + 0, s.x);
        atomicAdd(dst + 1, s.y);
        atomicAdd(dst + 2, s.z);
        atomicAdd(dst + 3, s.w);
    }
}

extern "C" void kernel_launch(void* const* d_in, const int* in_sizes, int n_in,
                              void* d_out, int out_size, void* d_ws, size_t ws_size,
                              hipStream_t stream) {
    const float* enc     = (const float*)d_in[0];
    const void*  mask    = d_in[1];
    const float* query   = (const float*)d_in[2];
    const float* cum     = (const float*)d_in[3];
    const float* conv_w  = (const float*)d_in[4];
    const float* conv_b  = (const float*)d_in[5];
    const float* Wq      = (const float*)d_in[6];
    const float* bq      = (const float*)d_in[7];
    const float* Wa      = (const float*)d_in[8];
    const float* ba      = (const float*)d_in[9];
    const float* score_w = (const float*)d_in[10];
    const float* score_b = (const float*)d_in[11];

    float* ctx_out   = (float*)d_out;                    // [B,H]   16384
    float* cum_out   = ctx_out + B_DIM * H_DIM;          // [B,T]   262144
    float* align_out = cum_out + B_DIM * T_DIM;          // [B,T]   262144

    float* G  = (float*)d_ws;                            // [k][h] 3968 floats (pad 4096)
    float* qb = G + 4096;                                // 16384 floats

    hipMemsetAsync(ctx_out, 0, B_DIM * H_DIM * sizeof(float), stream);
    k0_G<<<16, 256, 0, stream>>>(Wa, conv_w, G);
    k1_query<<<B_DIM, 512, 0, stream>>>(query, Wq, bq, Wa, conv_b, ba, score_b, qb);
    k2_score<<<dim3(T_DIM / TT, B_DIM), 256, 0, stream>>>(enc, cum, G, qb, score_w, align_out);
    k3_softmax<<<B_DIM, 256, 0, stream>>>(align_out, mask, cum, cum_out);
    k4_context<<<dim3(16, B_DIM), 256, 0, stream>>>(enc, align_out, ctx_out);
}

// Round 3
// 262.693 us; speedup vs baseline: 1.2289x; 1.0842x over previous
//
#include <hip/hip_runtime.h>
#include <stdint.h>

#define T_DIM 2048
#define B_DIM 128
#define H_DIM 128
#define QH_DIM 1024
#define NF 32
#define KW 31
#define TT 128         // t's per block in k2
#define NTILE (T_DIM / TT)   // 16 tiles per b

#define NEG_INF (-__builtin_inff())

__device__ __forceinline__ float fast_tanh(float x) {
    float e = __expf(2.0f * x);
    return 1.0f - 2.0f * __builtin_amdgcn_rcpf(1.0f + e);
}

// k0: G[k][h] = sum_f Wa[h,f] * conv_w[f,0,k]  — [k][h] layout for coalesced k2 staging
__global__ void k0_G(const float* __restrict__ Wa, const float* __restrict__ conv_w,
                     float* __restrict__ G) {
    int gid = blockIdx.x * blockDim.x + threadIdx.x;
    if (gid >= H_DIM * KW) return;
    int k = gid >> 7, h = gid & 127;
    float acc = 0.0f;
    #pragma unroll
    for (int f = 0; f < NF; ++f) acc = fmaf(Wa[h * NF + f], conv_w[f * KW + k], acc);
    G[gid] = acc;
}

// k1: qb[b,h] = query[b,:]·Wq[h,:] + bq[h] + ba[h] + score_b[h] + Wa[h,:]·conv_b
__global__ __launch_bounds__(512)
void k1_query(const float* __restrict__ query, const float* __restrict__ Wq,
              const float* __restrict__ bq, const float* __restrict__ Wa,
              const float* __restrict__ conv_b, const float* __restrict__ ba,
              const float* __restrict__ score_b, float* __restrict__ qb) {
    const int b = blockIdx.x, tid = threadIdx.x;
    const int h = tid & 127, qtr = tid >> 7;
    __shared__ __align__(16) float qrow[QH_DIM];
    __shared__ float partial[512];
    for (int i = tid; i < QH_DIM; i += 512) qrow[i] = query[b * QH_DIM + i];
    __syncthreads();
    const float4* wq4 = (const float4*)(Wq + (size_t)h * QH_DIM + qtr * 256);
    const float4* q4 = (const float4*)(qrow + qtr * 256);
    float acc = 0.0f;
    #pragma unroll 4
    for (int j = 0; j < 64; ++j) {
        float4 w = wq4[j], q = q4[j];
        acc += w.x * q.x + w.y * q.y + w.z * q.z + w.w * q.w;
    }
    if (qtr == 0) {
        float cb = bq[h] + ba[h] + score_b[h];
        #pragma unroll
        for (int f = 0; f < NF; ++f) cb = fmaf(Wa[h * NF + f], conv_b[f], cb);
        acc += cb;
    }
    partial[tid] = acc;
    __syncthreads();
    if (tid < 128) qb[b * H_DIM + h] = partial[h] + partial[h + 128] + partial[h + 256] + partial[h + 384];
}

// k2: fused score + masked online-softmax partials + context partials.
// Per block: one b, 128 t's. Wave wv owns t-range [wv*32, wv*32+32) in 4 sub-iters
// of 8 t's; lane owns h = {2l, 2l+1}. Per wave keeps running (m, l, o2[h-pair]);
// block combines 4 waves and writes (m_blk, l_blk, o_blk[128]) per tile to ws.
// Raw masked scores (−inf where masked) go to the alignment buffer for k5.
__global__ __launch_bounds__(256, 4)
void k2_score(const float* __restrict__ enc, const float* __restrict__ cum,
              const void* __restrict__ mask, const float* __restrict__ G,
              const float* __restrict__ qb, const float* __restrict__ score_w,
              float* __restrict__ s_out, float* __restrict__ o_part,
              float* __restrict__ ml_part) {
    const int b = blockIdx.x;          // b fastest-varying: contiguous enc slabs per tile
    const int tile = blockIdx.y;
    const int t0 = tile * TT;
    const int tid = threadIdx.x;
    const int l = tid & 63, wv = tid >> 6;

    __shared__ float Gs[KW * H_DIM];       // [k][h], 15872 B
    __shared__ float cw[TT + KW - 1];      // 158
    __shared__ float mbias[TT];            // 0 or -inf per t
    __shared__ float oc[4][H_DIM];
    __shared__ float mwl[4], lwl[4];

    // mask layout probe (per wave, redundant, wave-uniform result)
    {
        uint32_t u = ((const uint32_t*)mask)[l];
        unsigned long long hi = __ballot(u > 1u);
        unsigned long long nf = __ballot(u != 0u && u != 0x3f800000u);
        int layout = (hi == 0ull) ? 0 : ((nf == 0ull) ? 2 : 1);
        if (tid < TT) {
            int idx = b * T_DIM + t0 + tid;
            bool m;
            if (layout == 0)      m = ((const int32_t*)mask)[idx] != 0;
            else if (layout == 1) m = ((const uint8_t*)mask)[idx] != 0;
            else                  m = ((const float*)mask)[idx] != 0.0f;
            mbias[tid] = m ? NEG_INF : 0.0f;
        }
    }
    for (int i = tid; i < KW * H_DIM; i += 256) Gs[i] = G[i];
    if (tid < TT + KW - 1) {
        int t = t0 - (KW / 2) + tid;
        cw[tid] = (t >= 0 && t < T_DIM) ? cum[b * T_DIM + t] : 0.0f;
    }
    __syncthreads();

    const float2 base = *(const float2*)(qb + b * H_DIM + 2 * l);
    const float2 w2 = *(const float2*)(score_w + 2 * l);

    float m_w = NEG_INF, l_w = 0.0f;
    float ox = 0.0f, oy = 0.0f;

    #pragma unroll
    for (int si = 0; si < 4; ++si) {
        const int cbase = wv * 32 + si * 8;        // t-offset within tile
        float2 acc[8];
        #pragma unroll
        for (int it = 0; it < 8; ++it) acc[it] = base;

        // FIR chunk A: k = 0..15, taps cbase+0..22
        {
            float tp[23];
            #pragma unroll
            for (int j = 0; j < 23; ++j) tp[j] = cw[cbase + j];
            #pragma unroll
            for (int k = 0; k < 16; ++k) {
                const float2 gk = *(const float2*)(&Gs[k * H_DIM + 2 * l]);
                #pragma unroll
                for (int it = 0; it < 8; ++it) {
                    acc[it].x = fmaf(gk.x, tp[k + it], acc[it].x);
                    acc[it].y = fmaf(gk.y, tp[k + it], acc[it].y);
                }
            }
        }
        // FIR chunk B: k = 16..30, taps cbase+16..37
        {
            float tp[22];
            #pragma unroll
            for (int j = 0; j < 22; ++j) tp[j] = cw[cbase + 16 + j];
            #pragma unroll
            for (int k = 16; k < 31; ++k) {
                const float2 gk = *(const float2*)(&Gs[k * H_DIM + 2 * l]);
                #pragma unroll
                for (int it = 0; it < 8; ++it) {
                    acc[it].x = fmaf(gk.x, tp[k - 16 + it], acc[it].x);
                    acc[it].y = fmaf(gk.y, tp[k - 16 + it], acc[it].y);
                }
            }
        }

        // score + reduce + online softmax fold
        const float* ep = enc + ((size_t)(t0 + cbase) * B_DIM + b) * H_DIM + 2 * l;
        float ex[8], ey[8], s_arr[8];
        #pragma unroll
        for (int it = 0; it < 8; ++it) {
            const float2 e2 = *(const float2*)(ep + (size_t)it * (B_DIM * H_DIM));
            ex[it] = e2.x; ey[it] = e2.y;
            float p = w2.x * fast_tanh(acc[it].x + e2.x)
                    + w2.y * fast_tanh(acc[it].y + e2.y);
            #pragma unroll
            for (int m = 32; m >= 1; m >>= 1) p += __shfl_xor(p, m, 64);
            s_arr[it] = p + mbias[cbase + it];   // -inf if masked
        }
        // store masked scores (lanes 0..7)
        float sv = s_arr[0];
        #pragma unroll
        for (int it = 1; it < 8; ++it) sv = (l == it) ? s_arr[it] : sv;
        if (l < 8) s_out[b * T_DIM + t0 + cbase + l] = sv;
        // online update
        float m8 = s_arr[0];
        #pragma unroll
        for (int it = 1; it < 8; ++it) m8 = fmaxf(m8, s_arr[it]);
        const float m_new = fmaxf(m_w, m8);
        const float m_use = (m_new == NEG_INF) ? 0.0f : m_new;
        const float alpha = __expf(m_w - m_use);
        float lsum = 0.0f, osx = 0.0f, osy = 0.0f;
        #pragma unroll
        for (int it = 0; it < 8; ++it) {
            const float e = __expf(s_arr[it] - m_use);
            lsum += e;
            osx = fmaf(e, ex[it], osx);
            osy = fmaf(e, ey[it], osy);
        }
        l_w = fmaf(l_w, alpha, lsum);
        ox = fmaf(ox, alpha, osx);
        oy = fmaf(oy, alpha, osy);
        m_w = m_new;
    }

    // combine 4 waves
    oc[wv][2 * l] = ox;
    oc[wv][2 * l + 1] = oy;
    if (l == 0) { mwl[wv] = m_w; lwl[wv] = l_w; }
    __syncthreads();
    if (tid < H_DIM) {
        const float mb = fmaxf(fmaxf(mwl[0], mwl[1]), fmaxf(mwl[2], mwl[3]));
        const float mu = (mb == NEG_INF) ? 0.0f : mb;
        const float b0 = __expf(mwl[0] - mu), b1 = __expf(mwl[1] - mu);
        const float b2 = __expf(mwl[2] - mu), b3 = __expf(mwl[3] - mu);
        const float o = oc[0][tid] * b0 + oc[1][tid] * b1 + oc[2][tid] * b2 + oc[3][tid] * b3;
        const int tbase = b * NTILE + tile;
        o_part[tbase * H_DIM + tid] = o;
        if (tid == 0) {
            ml_part[tbase * 2] = mb;
            ml_part[tbase * 2 + 1] = lwl[0] * b0 + lwl[1] * b1 + lwl[2] * b2 + lwl[3] * b3;
        }
    }
}

// k5: per-b global combine: M, L from tile (m,l); ctx from tile o's;
// alignment + cumulative from stored raw scores.
__global__ __launch_bounds__(256)
void k5_final(float* __restrict__ s_align, const float* __restrict__ cum_in,
              float* __restrict__ cum_out, const float* __restrict__ o_part,
              const float* __restrict__ ml_part, float* __restrict__ ctx) {
    const int b = blockIdx.x, tid = threadIdx.x;
    __shared__ float sm[NTILE], sl[NTILE], sb[NTILE];
    if (tid < NTILE) {
        sm[tid] = ml_part[(b * NTILE + tid) * 2];
        sl[tid] = ml_part[(b * NTILE + tid) * 2 + 1];
    }
    __syncthreads();
    float M = sm[0];
    #pragma unroll
    for (int i = 1; i < NTILE; ++i) M = fmaxf(M, sm[i]);
    const float M_use = (M == NEG_INF) ? 0.0f : M;
    if (tid < NTILE) sb[tid] = __expf(sm[tid] - M_use);
    __syncthreads();
    float L = 0.0f;
    #pragma unroll
    for (int i = 0; i < NTILE; ++i) L = fmaf(sl[i], sb[i], L);
    const float invL = 1.0f / L;
    if (tid < H_DIM) {
        float o = 0.0f;
        #pragma unroll
        for (int i = 0; i < NTILE; ++i)
            o = fmaf(o_part[(b * NTILE + i) * H_DIM + tid], sb[i], o);
        ctx[b * H_DIM + tid] = o * invL;
    }
    #pragma unroll
    for (int j = 0; j < 8; ++j) {
        const int idx = b * T_DIM + tid + j * 256;
        const float a = __expf(s_align[idx] - M_use) * invL;
        s_align[idx] = a;
        cum_out[idx] = cum_in[idx] + a;
    }
}

extern "C" void kernel_launch(void* const* d_in, const int* in_sizes, int n_in,
                              void* d_out, int out_size, void* d_ws, size_t ws_size,
                              hipStream_t stream) {
    const float* enc     = (const float*)d_in[0];
    const void*  mask    = d_in[1];
    const float* query   = (const float*)d_in[2];
    const float* cum     = (const float*)d_in[3];
    const float* conv_w  = (const float*)d_in[4];
    const float* conv_b  = (const float*)d_in[5];
    const float* Wq      = (const float*)d_in[6];
    const float* bq      = (const float*)d_in[7];
    const float* Wa      = (const float*)d_in[8];
    const float* ba      = (const float*)d_in[9];
    const float* score_w = (const float*)d_in[10];
    const float* score_b = (const float*)d_in[11];

    float* ctx_out   = (float*)d_out;                    // [B,H]   16384
    float* cum_out   = ctx_out + B_DIM * H_DIM;          // [B,T]   262144
    float* align_out = cum_out + B_DIM * T_DIM;          // [B,T]   262144

    float* G      = (float*)d_ws;                        // [k][h]  4096 (pad)
    float* qb     = G + 4096;                            // [B,H]   16384
    float* o_part = qb + B_DIM * H_DIM;                  // [B,NTILE,H] 262144
    float* ml     = o_part + B_DIM * NTILE * H_DIM;      // [B,NTILE,2] 4096

    k0_G<<<16, 256, 0, stream>>>(Wa, conv_w, G);
    k1_query<<<B_DIM, 512, 0, stream>>>(query, Wq, bq, Wa, conv_b, ba, score_b, qb);
    k2_score<<<dim3(B_DIM, NTILE), 256, 0, stream>>>(enc, cum, mask, G, qb, score_w,
                                                     align_out, o_part, ml);
    k5_final<<<B_DIM, 256, 0, stream>>>(align_out, cum, cum_out, o_part, ml, ctx_out);
}